// Round 1
// baseline (150.848 us; speedup 1.0000x reference)
//
#include <hip/hip_runtime.h>
#include <hip/hip_bf16.h>

// TT linear: y[b, o01*64+o23] = sum_{r2,i01,i23} W01[i01,o01,r2] * x[b,i01*64+i23] * W23[r2,i23,o23]
// Per row b: Y_b = sum_{r2} U_{r2}^T (64x64) @ X_b (64x64) @ V_{r2} (64x64)
// One wave per row. GEMM1 computes T^T = X^T @ U (MFMA D-layout gives free transpose on the
// LDS write), GEMM2 does Y += T @ V. Weights pre-packed in MFMA B-frag order in d_ws.

typedef __attribute__((ext_vector_type(8))) short bf16x8;   // 8 bf16 = 4 VGPRs
typedef __attribute__((ext_vector_type(4))) float f32x4;

#define MFMA16(a, b, c) __builtin_amdgcn_mfma_f32_16x16x32_bf16(a, b, c, 0, 0, 0)

__device__ __forceinline__ short f2bf(float f) {
    union { float f; unsigned u; } v{f};
    unsigned r = v.u + 0x7fff + ((v.u >> 16) & 1);   // round-to-nearest-even
    return (short)(r >> 16);
}

// ---------------------------------------------------------------------------
// Prep: contract cores -> W01 (64x64x8), W23 (8x64x64), write bf16 packed in
// MFMA B-fragment order: elem e = [isV][r2][nt*2+kt][lane][j]
//   k = kt*32 + (lane>>4)*8 + j   (K index: i01 for U, i23 for V)
//   n = nt*16 + (lane&15)         (N index: o01 for U, o23 for V)
// ---------------------------------------------------------------------------
__global__ void tt_prep(const float* __restrict__ c0, const float* __restrict__ c1,
                        const float* __restrict__ c2, const float* __restrict__ c3,
                        short* __restrict__ wpack) {
    int e    = blockIdx.x * 256 + threadIdx.x;       // 0..65535
    int isV  = e >> 15;
    int idx  = e & 32767;
    int r2   = idx >> 12;
    int rem  = idx & 4095;
    int frag = rem >> 9;                              // nt*2+kt
    int lane = (rem >> 3) & 63;
    int j    = rem & 7;
    int nt = frag >> 1, kt = frag & 1;
    int k = kt * 32 + (lane >> 4) * 8 + j;
    int n = nt * 16 + (lane & 15);
    float acc = 0.f;
    if (!isV) {
        // U_{r2}[i01][o01] = W01[i01,o01,r2] = sum_r1 c0[0,i0,o0,r1]*c1[r1,i1,o1,r2]
        int i0 = k >> 3, i1 = k & 7, o0 = n >> 3, o1 = n & 7;
        #pragma unroll
        for (int r1 = 0; r1 < 8; ++r1)
            acc += c0[(i0 * 8 + o0) * 8 + r1] * c1[((r1 * 8 + i1) * 8 + o1) * 8 + r2];
    } else {
        // V_{r2}[i23][o23] = W23[r2,i23,o23] = sum_r3 c2[r2,i2,o2,r3]*c3[r3,i3,o3,0]
        int i2 = k >> 3, i3 = k & 7, o2 = n >> 3, o3 = n & 7;
        #pragma unroll
        for (int r3 = 0; r3 < 8; ++r3)
            acc += c2[((r2 * 8 + i2) * 8 + o2) * 8 + r3] * c3[(r3 * 8 + i3) * 8 + o3];
    }
    wpack[e] = f2bf(acc);
}

// ---------------------------------------------------------------------------
// Main: 512 blocks x 512 threads (8 waves). Wave w of block g handles b = g*8+w.
// ---------------------------------------------------------------------------
__global__ __launch_bounds__(512, 2)
void tt_main(const float* __restrict__ x, const float* __restrict__ bias,
             const short* __restrict__ wpack, float* __restrict__ out) {
    __shared__ short tbuf[8 * 4096];                  // per-wave private 64x64 bf16 T
    const int tid  = threadIdx.x;
    const int wave = tid >> 6;
    const int lane = tid & 63;
    const int lo   = lane & 15;
    const int q    = lane >> 4;
    const int b    = blockIdx.x * 8 + wave;

    short* T = &tbuf[wave * 4096];

    // ---- X^T A-frags: xa[mt][kt], A[m=i23][k=i01], m=lo, k=q*8+j ----
    bf16x8 xa[4][2];
    const float* xb = x + (size_t)b * 4096;
    #pragma unroll
    for (int mt = 0; mt < 4; ++mt)
        #pragma unroll
        for (int kt = 0; kt < 2; ++kt)
            #pragma unroll
            for (int j = 0; j < 8; ++j) {
                int i01 = kt * 32 + q * 8 + j;
                int i23 = mt * 16 + lo;
                xa[mt][kt][j] = f2bf(xb[i01 * 64 + i23]);
            }

    f32x4 yacc[4][4];
    #pragma unroll
    for (int m = 0; m < 4; ++m)
        #pragma unroll
        for (int n = 0; n < 4; ++n)
            yacc[m][n] = f32x4{0.f, 0.f, 0.f, 0.f};

    const bf16x8* Up = (const bf16x8*)wpack;              // [ (r2*8+frag)*64 + lane ]
    const bf16x8* Vp = (const bf16x8*)(wpack + 32768);

    for (int r2 = 0; r2 < 8; ++r2) {
        // U B-frags
        bf16x8 uf[4][2];
        #pragma unroll
        for (int nt = 0; nt < 4; ++nt)
            #pragma unroll
            for (int kt = 0; kt < 2; ++kt)
                uf[nt][kt] = Up[(r2 * 8 + nt * 2 + kt) * 64 + lane];

        // GEMM1: T^T[i23][o01] = X^T @ U_{r2}; write transposed into LDS as T[o01][i23]
        #pragma unroll
        for (int mt = 0; mt < 4; ++mt) {
            f32x4 tacc[4];
            #pragma unroll
            for (int nt = 0; nt < 4; ++nt) tacc[nt] = f32x4{0.f, 0.f, 0.f, 0.f};
            #pragma unroll
            for (int kt = 0; kt < 2; ++kt)
                #pragma unroll
                for (int nt = 0; nt < 4; ++nt)
                    tacc[nt] = MFMA16(xa[mt][kt], uf[nt][kt], tacc[nt]);
            // D tile (mt,nt): value at i23 = mt*16+q*4+r, o01 = nt*16+lo  -> 4 consecutive
            // i23 in T[o01][i23] row-major (stride 128B), XOR-swizzled to kill bank conflicts
            #pragma unroll
            for (int nt = 0; nt < 4; ++nt) {
                int o01 = nt * 16 + lo;
                int i23 = mt * 16 + q * 4;
                unsigned w0 = (unsigned)(unsigned short)f2bf(tacc[nt][0]) |
                              ((unsigned)(unsigned short)f2bf(tacc[nt][1]) << 16);
                unsigned w1 = (unsigned)(unsigned short)f2bf(tacc[nt][2]) |
                              ((unsigned)(unsigned short)f2bf(tacc[nt][3]) << 16);
                int byteoff = (o01 * 128 + i23 * 2) ^ ((o01 & 7) << 4);
                *(uint2*)((char*)T + byteoff) = make_uint2(w0, w1);
            }
        }

        // V B-frags
        bf16x8 vf[4][2];
        #pragma unroll
        for (int nt = 0; nt < 4; ++nt)
            #pragma unroll
            for (int kt = 0; kt < 2; ++kt)
                vf[nt][kt] = Vp[(r2 * 8 + nt * 2 + kt) * 64 + lane];

        // GEMM2: Y += T @ V_{r2};  A-frag: row o01 = lo, k = i23
        #pragma unroll
        for (int kt = 0; kt < 2; ++kt) {
            bf16x8 ta[4];
            #pragma unroll
            for (int mt = 0; mt < 4; ++mt) {
                int o01 = mt * 16 + lo;
                int i23 = kt * 32 + q * 8;
                int byteoff = (o01 * 128 + i23 * 2) ^ ((o01 & 7) << 4);
                ta[mt] = *(const bf16x8*)((const char*)T + byteoff);
            }
            #pragma unroll
            for (int mt = 0; mt < 4; ++mt)
                #pragma unroll
                for (int nt = 0; nt < 4; ++nt)
                    yacc[mt][nt] = MFMA16(ta[mt], vf[nt][kt], yacc[mt][nt]);
        }
    }

    // Epilogue: D tile (mt,nt): o01 = mt*16+q*4+r, o23 = nt*16+lo
    float* ob = out + (size_t)b * 4096;
    #pragma unroll
    for (int mt = 0; mt < 4; ++mt)
        #pragma unroll
        for (int nt = 0; nt < 4; ++nt)
            #pragma unroll
            for (int r = 0; r < 4; ++r) {
                int o01 = mt * 16 + q * 4 + r;
                int o23 = nt * 16 + lo;
                int no  = o01 * 64 + o23;
                ob[no] = yacc[mt][nt][r] + bias[no];
            }
}

extern "C" void kernel_launch(void* const* d_in, const int* in_sizes, int n_in,
                              void* d_out, int out_size, void* d_ws, size_t ws_size,
                              hipStream_t stream) {
    const float* x    = (const float*)d_in[0];
    const float* c0   = (const float*)d_in[1];
    const float* c1   = (const float*)d_in[2];
    const float* c2   = (const float*)d_in[3];
    const float* c3   = (const float*)d_in[4];
    const float* bias = (const float*)d_in[5];
    short* wpack = (short*)d_ws;                       // 65536 bf16 = 128 KB

    tt_prep<<<256, 256, 0, stream>>>(c0, c1, c2, c3, wpack);
    tt_main<<<512, 512, 0, stream>>>(x, bias, wpack, (float*)d_out);
}

// Round 5
// 145.704 us; speedup vs baseline: 1.0353x; 1.0353x over previous
//
#include <hip/hip_runtime.h>
#include <hip/hip_bf16.h>

// TT linear: y[b, o01*64+o23] = sum_{r2} (U_{r2}^T @ X_b @ V_{r2})[o01][o23]
//   U_{r2}[i01][o01] = sum_{r1} c0[0,i0,o0,r1] c1[r1,i1,o1,r2]   (i01=i0*8+i1, o01=o0*8+o1)
//   V_{r2}[i23][o23] = sum_{r3} c2[r2,i2,o2,r3] c3[r3,i3,o3,0]
// Per wave (one batch row): GEMM1 S = X*V_{r2} (A=x loaded as contiguous-k frags),
// exchange S (D-layout) -> B-operand frags via v_permlane32_swap, GEMM2 Y += U^T*S.
// No LDS, no barriers. Weights pre-packed in MFMA 32x32x16 fragment order in d_ws.

typedef __attribute__((ext_vector_type(8))) short bf16x8;    // 8 bf16 = 4 VGPRs
typedef __attribute__((ext_vector_type(16))) float f32x16;   // 32x32 MFMA acc

#define MFMA32(a, b, c) __builtin_amdgcn_mfma_f32_32x32x16_bf16(a, b, c, 0, 0, 0)

__device__ __forceinline__ unsigned short bfu(float f) {
    __hip_bfloat16 h = __float2bfloat16(f);                   // RNE, fuses to v_cvt_pk
    return *reinterpret_cast<unsigned short*>(&h);
}
__device__ __forceinline__ unsigned pk2(float a, float b) {
    return (unsigned)bfu(a) | ((unsigned)bfu(b) << 16);
}

// ---------------------------------------------------------------------------
// Prep: contract cores, write bf16 packed in 32x32x16 MFMA fragment order.
// First 32768: V B-frags [r2][nt][ks1][lane][j]:  k=i23=ks1*16+(lane>>5)*8+j, n=o23=nt*32+(lane&31)
// Next  32768: U A-frags [r2][mt2][kt][ks2][lane][j]: k=i01=kt*32+ks2*16+(lane>>5)*8+j, m=o01=mt2*32+(lane&31)
// ---------------------------------------------------------------------------
__global__ void tt_prep(const float* __restrict__ c0, const float* __restrict__ c1,
                        const float* __restrict__ c2, const float* __restrict__ c3,
                        unsigned short* __restrict__ wpack) {
    int e    = blockIdx.x * 256 + threadIdx.x;                // 0..65535
    int lane = (e >> 3) & 63;
    int j    = e & 7;
    int hi   = lane >> 5, l31 = lane & 31;
    float acc = 0.f;
    if (e < 32768) {
        int idx = e;
        int r2  = idx >> 12;
        int nt  = (idx >> 11) & 1;
        int ks1 = (idx >> 9) & 3;
        int i23 = ks1 * 16 + hi * 8 + j;
        int o23 = nt * 32 + l31;
        int i2 = i23 >> 3, i3 = i23 & 7, o2 = o23 >> 3, o3 = o23 & 7;
        #pragma unroll
        for (int r3 = 0; r3 < 8; ++r3)
            acc += c2[((r2 * 8 + i2) * 8 + o2) * 8 + r3] * c3[(r3 * 8 + i3) * 8 + o3];
    } else {
        int idx = e - 32768;
        int r2  = idx >> 12;
        int mt2 = (idx >> 11) & 1;
        int kt  = (idx >> 10) & 1;
        int ks2 = (idx >> 9) & 1;
        int i01 = kt * 32 + ks2 * 16 + hi * 8 + j;
        int o01 = mt2 * 32 + l31;
        int i0 = i01 >> 3, i1 = i01 & 7, o0 = o01 >> 3, o1 = o01 & 7;
        #pragma unroll
        for (int r1 = 0; r1 < 8; ++r1)
            acc += c0[(i0 * 8 + o0) * 8 + r1] * c1[((r1 * 8 + i1) * 8 + o1) * 8 + r2];
    }
    wpack[e] = bfu(acc);
}

// ---------------------------------------------------------------------------
// Main: 1024 blocks x 256 threads (4 waves). Wave w of block g: row b = g*4+w.
// ---------------------------------------------------------------------------
__global__ __launch_bounds__(256, 2)
void tt_main(const float* __restrict__ x, const float* __restrict__ bias,
             const unsigned short* __restrict__ wpack, float* __restrict__ out) {
    const int lane = threadIdx.x & 63;
    const int wave = threadIdx.x >> 6;
    const int b    = blockIdx.x * 4 + wave;
    const int l31  = lane & 31;
    const int hi   = lane >> 5;

    const float* xb = x + (size_t)b * 4096;

    // ---- x A-frags: xa[mt][ks1], a[j] = x[i01=mt*32+l31][i23=ks1*16+hi*8+j] ----
    bf16x8 xa[2][4];
    #pragma unroll
    for (int mt = 0; mt < 2; ++mt)
        #pragma unroll
        for (int ks1 = 0; ks1 < 4; ++ks1) {
            const float* p = xb + (mt * 32 + l31) * 64 + ks1 * 16 + hi * 8;
            float4 u0 = *(const float4*)p;
            float4 u1 = *(const float4*)(p + 4);
            union { unsigned w[4]; bf16x8 v; } t;
            t.w[0] = pk2(u0.x, u0.y);
            t.w[1] = pk2(u0.z, u0.w);
            t.w[2] = pk2(u1.x, u1.y);
            t.w[3] = pk2(u1.z, u1.w);
            xa[mt][ks1] = t.v;
        }

    f32x16 yacc[2][2];
    #pragma unroll
    for (int i = 0; i < 2; ++i)
        #pragma unroll
        for (int k = 0; k < 2; ++k)
            yacc[i][k] = (f32x16)0.0f;

    const bf16x8* Vp = (const bf16x8*)wpack;                       // [r2][nt][ks1][lane]
    const bf16x8* Up = (const bf16x8*)(wpack + 32768);             // [r2][mt2][kt][ks2][lane]

    for (int r2 = 0; r2 < 8; ++r2) {
        bf16x8 vf[2][4];
        #pragma unroll
        for (int nt = 0; nt < 2; ++nt)
            #pragma unroll
            for (int ks1 = 0; ks1 < 4; ++ks1)
                vf[nt][ks1] = Vp[((r2 * 2 + nt) * 4 + ks1) * 64 + lane];

        #pragma unroll
        for (int mt = 0; mt < 2; ++mt) {
            bf16x8 uf[2][2];                                       // [mt2][ks2], kt = mt
            #pragma unroll
            for (int mt2 = 0; mt2 < 2; ++mt2)
                #pragma unroll
                for (int ks2 = 0; ks2 < 2; ++ks2)
                    uf[mt2][ks2] = Up[(((r2 * 2 + mt2) * 2 + mt) * 2 + ks2) * 64 + lane];

            #pragma unroll
            for (int nt = 0; nt < 2; ++nt) {
                // GEMM1: S tile (mt,nt) = X * V_{r2}
                f32x16 s = (f32x16)0.0f;
                #pragma unroll
                for (int ks1 = 0; ks1 < 4; ++ks1)
                    s = MFMA32(xa[mt][ks1], vf[nt][ks1], s);

                // Exchange: D-layout (4-row groups per half-wave) -> B-frag
                // (8-row groups). (w0,w2)=swap(pk(d0,d1),pk(d4,d5)); (w1,w3)=swap(pk(d2,d3),pk(d6,d7)).
                bf16x8 bf[2];
                #pragma unroll
                for (int ks2 = 0; ks2 < 2; ++ks2) {
                    unsigned A0 = pk2(s[8 * ks2 + 0], s[8 * ks2 + 1]);
                    unsigned B0 = pk2(s[8 * ks2 + 2], s[8 * ks2 + 3]);
                    unsigned A1 = pk2(s[8 * ks2 + 4], s[8 * ks2 + 5]);
                    unsigned B1 = pk2(s[8 * ks2 + 6], s[8 * ks2 + 7]);
                    auto rA = __builtin_amdgcn_permlane32_swap((int)A0, (int)A1, false, false);
                    auto rB = __builtin_amdgcn_permlane32_swap((int)B0, (int)B1, false, false);
                    union { unsigned w[4]; bf16x8 v; } t;
                    t.w[0] = (unsigned)rA[0];
                    t.w[1] = (unsigned)rB[0];
                    t.w[2] = (unsigned)rA[1];
                    t.w[3] = (unsigned)rB[1];
                    bf[ks2] = t.v;
                }

                // GEMM2: Y[mt2][nt] += U^T frag (kt=mt) * S frag
                #pragma unroll
                for (int mt2 = 0; mt2 < 2; ++mt2)
                    #pragma unroll
                    for (int ks2 = 0; ks2 < 2; ++ks2)
                        yacc[mt2][nt] = MFMA32(uf[mt2][ks2], bf[ks2], yacc[mt2][nt]);
            }
        }
    }

    // Epilogue: D layout row = (r&3)+8*(r>>2)+4*hi (+32*mt2), col = l31 (+32*nt)
    float* ob = out + (size_t)b * 4096;
    #pragma unroll
    for (int mt2 = 0; mt2 < 2; ++mt2)
        #pragma unroll
        for (int nt = 0; nt < 2; ++nt)
            #pragma unroll
            for (int r = 0; r < 16; ++r) {
                int o01 = mt2 * 32 + (r & 3) + 8 * (r >> 2) + 4 * hi;
                int o23 = nt * 32 + l31;
                int off = o01 * 64 + o23;
                ob[off] = yacc[mt2][nt][r] + bias[off];
            }
}

extern "C" void kernel_launch(void* const* d_in, const int* in_sizes, int n_in,
                              void* d_out, int out_size, void* d_ws, size_t ws_size,
                              hipStream_t stream) {
    const float* x    = (const float*)d_in[0];
    const float* c0   = (const float*)d_in[1];
    const float* c1   = (const float*)d_in[2];
    const float* c2   = (const float*)d_in[3];
    const float* c3   = (const float*)d_in[4];
    const float* bias = (const float*)d_in[5];
    unsigned short* wpack = (unsigned short*)d_ws;                 // 64K bf16 = 128 KB

    tt_prep<<<256, 256, 0, stream>>>(c0, c1, c2, c3, wpack);
    tt_main<<<1024, 256, 0, stream>>>(x, bias, wpack, (float*)d_out);
}